// Round 16
// baseline (177.248 us; speedup 1.0000x reference)
//
#include <hip/hip_runtime.h>

typedef __bf16 bf16x8 __attribute__((ext_vector_type(8)));
typedef __bf16 bf16x2 __attribute__((ext_vector_type(2)));
typedef float f32x4 __attribute__((ext_vector_type(4)));
typedef float f32x16 __attribute__((ext_vector_type(16)));
typedef unsigned short ushort;

__device__ __forceinline__ int4 cvt8(float4 a, float4 b) {
  bf16x8 v;
  v[0] = (__bf16)a.x; v[1] = (__bf16)a.y; v[2] = (__bf16)a.z; v[3] = (__bf16)a.w;
  v[4] = (__bf16)b.x; v[5] = (__bf16)b.y; v[6] = (__bf16)b.z; v[7] = (__bf16)b.w;
  return __builtin_bit_cast(int4, v);
}

__device__ __forceinline__ void gld16(const void* g, void* l) {
  __builtin_amdgcn_global_load_lds(
      (const __attribute__((address_space(1))) void*)g,
      (__attribute__((address_space(3))) void*)l, 16, 0, 0);
}

// pack 2 f32 -> 1 dword of 2 bf16 (compiler emits v_cvt_pk_bf16_f32)
__device__ __forceinline__ unsigned pkbf(float a, float b) {
  bf16x2 v;
  v[0] = (__bf16)a;
  v[1] = (__bf16)b;
  return __builtin_bit_cast(unsigned, v);
}

// exchange: after call a = [a_lo | b_lo], b = [a_hi | b_hi] (32-lane halves)
#if __has_builtin(__builtin_amdgcn_permlane32_swap)
typedef unsigned u32x2 __attribute__((ext_vector_type(2)));
__device__ __forceinline__ void plswap(unsigned& a, unsigned& b, int hi) {
  (void)hi;
  u32x2 r = __builtin_amdgcn_permlane32_swap(a, b, false, false);
  a = r[0]; b = r[1];
}
#else
__device__ __forceinline__ void plswap(unsigned& a, unsigned& b, int hi) {
  const unsigned pa = (unsigned)__shfl_xor((int)a, 32);
  const unsigned pb = (unsigned)__shfl_xor((int)b, 32);
  const unsigned x = hi ? pb : a;
  const unsigned y = hi ? b : pa;
  a = x; b = y;
}
#endif

__device__ __forceinline__ f32x16 mfma32(bf16x8 a, bf16x8 b, f32x16 c) {
  return __builtin_amdgcn_mfma_f32_32x32x16_bf16(a, b, c, 0, 0, 0);
}

// 4 weight matrices fp32 -> bf16 in one launch (grid.y picks the matrix)
__global__ __launch_bounds__(256) void cvt4_k(const float* __restrict__ i0,
                                              const float* __restrict__ i1,
                                              const float* __restrict__ i2,
                                              const float* __restrict__ i3,
                                              ushort* __restrict__ o, int n8) {
  const int z = blockIdx.y;
  const float* in = (z == 0) ? i0 : (z == 1) ? i1 : (z == 2) ? i2 : i3;
  ushort* out = o + (size_t)z * 1024 * 1024;
  int i = blockIdx.x * 256 + threadIdx.x;
  if (i >= n8) return;
  const float4* p = (const float4*)in + (size_t)i * 2;
  *(int4*)(out + (size_t)i * 8) = cvt8(p[0], p[1]);
}

// C = (A @ W^T + bias) * oscale. M=8192, N=K=1024. Tile 128x128, BK=64.
// DOUBLE-BUFFERED (T14). XCD-aware 1D grid (512 blocks).
// AMODE 0: A fp32 (named-reg prefetch + cvt); 1: A bf16 (global_load_lds).
// OMODE 0: bf16 [B,H,S,HD]; 2: fp32 [M,N];
// OMODE 3: bf16 [B,H,HD,S] via LDS transpose (coalesced stores along S).
template <int AMODE, int OMODE>
__global__ __launch_bounds__(256) void gemm_k(const void* __restrict__ A,
                                              const ushort* __restrict__ W,
                                              const float* __restrict__ bias,
                                              void* __restrict__ Out,
                                              float oscale) {
  constexpr int K = 1024;
  __shared__ __align__(16) char lds_all[4][16384];  // lA = [0..1], lB = [2..3]
#define lAbuf(b) (lds_all[(b)])
#define lBbuf(b) (lds_all[2 + (b)])
  const int t = threadIdx.x;
  const int l = t & 63;
  const int w = t >> 6;
  const int wr = w >> 1, wc = w & 1;
  const int bid = blockIdx.x;
  const int xcd = bid & 7, j = bid >> 3;
  const int m0 = (xcd * 8 + (j >> 3)) * 128;
  const int n0 = (j & 7) * 128;
  const int srow = l >> 3;
  const int scol = ((l & 7) ^ srow) << 3;
  const int ar = t >> 3;
  const int ac = (t & 7) * 8;
  const float* Abase = (const float*)A + (size_t)(m0 + ar) * K + ac;
  const int adst = ar * 128 + ((ac * 2) ^ ((ar & 7) << 4));
  float4 a0, a1, a2, a3, a4, a5, a6, a7;  // named -> stay in VGPRs

#define LOAD_A(k0)                                         \
  do {                                                     \
    const float* ap = Abase + (k0);                        \
    a0 = *(const float4*)(ap);                             \
    a1 = *(const float4*)(ap + 4);                         \
    a2 = *(const float4*)(ap + 32 * K);                    \
    a3 = *(const float4*)(ap + 32 * K + 4);                \
    a4 = *(const float4*)(ap + 64 * K);                    \
    a5 = *(const float4*)(ap + 64 * K + 4);                \
    a6 = *(const float4*)(ap + 96 * K);                    \
    a7 = *(const float4*)(ap + 96 * K + 4);                \
  } while (0)
#define CVT_WRITE(b)                                       \
  do {                                                     \
    *(int4*)(lAbuf(b) + adst) = cvt8(a0, a1);              \
    *(int4*)(lAbuf(b) + adst + 32 * 128) = cvt8(a2, a3);   \
    *(int4*)(lAbuf(b) + adst + 64 * 128) = cvt8(a4, a5);   \
    *(int4*)(lAbuf(b) + adst + 96 * 128) = cvt8(a6, a7);   \
  } while (0)
#define GLD_A(k0, b)                                                        \
  do {                                                                      \
    _Pragma("unroll") for (int i = 0; i < 4; ++i) {                         \
      const int chunk = w * 4 + i;                                          \
      gld16((const ushort*)A + (size_t)(m0 + chunk * 8 + srow) * K + (k0) + \
                scol,                                                       \
            lAbuf(b) + chunk * 1024);                                       \
    }                                                                       \
  } while (0)
#define GLD_W(k0, b)                                                         \
  do {                                                                       \
    _Pragma("unroll") for (int i = 0; i < 4; ++i) {                          \
      const int chunk = w * 4 + i;                                           \
      gld16(W + (size_t)(n0 + chunk * 8 + srow) * K + (k0) + scol,           \
            lBbuf(b) + chunk * 1024);                                        \
    }                                                                        \
  } while (0)

  f32x4 acc[4][4];
#pragma unroll
  for (int i = 0; i < 4; ++i)
#pragma unroll
    for (int j2 = 0; j2 < 4; ++j2) acc[i][j2] = (f32x4){0.f, 0.f, 0.f, 0.f};

  if constexpr (AMODE == 0) {
    LOAD_A(0);
    CVT_WRITE(0);
  } else {
    GLD_A(0, 0);
  }
  GLD_W(0, 0);
  __syncthreads();

  int buf = 0;
  for (int k0 = 0; k0 < K; k0 += 64) {
    const int nk = k0 + 64;
    if (nk < K) {
      if constexpr (AMODE == 0) LOAD_A(nk);
      else GLD_A(nk, buf ^ 1);
      GLD_W(nk, buf ^ 1);
    }
#pragma unroll
    for (int ks = 0; ks < 2; ++ks) {
      const int kb = ks * 64 + ((l >> 4) << 4);
      bf16x8 af[4], bfv[4];
#pragma unroll
      for (int i = 0; i < 4; ++i) {
        const int row = wr * 64 + i * 16 + (l & 15);
        af[i] = *(const bf16x8*)(lAbuf(buf) + row * 128 + (kb ^ ((row & 7) << 4)));
      }
#pragma unroll
      for (int j2 = 0; j2 < 4; ++j2) {
        const int row = wc * 64 + j2 * 16 + (l & 15);
        bfv[j2] = *(const bf16x8*)(lBbuf(buf) + row * 128 + (kb ^ ((row & 7) << 4)));
      }
#pragma unroll
      for (int i = 0; i < 4; ++i)
#pragma unroll
        for (int j2 = 0; j2 < 4; ++j2)
          acc[i][j2] = __builtin_amdgcn_mfma_f32_16x16x32_bf16(af[i], bfv[j2],
                                                               acc[i][j2], 0, 0, 0);
    }
    if constexpr (AMODE == 0) {
      if (nk < K) CVT_WRITE(buf ^ 1);
    }
    __syncthreads();
    buf ^= 1;
  }
#undef LOAD_A
#undef CVT_WRITE
#undef GLD_A
#undef GLD_W

  if constexpr (OMODE == 3) {
    ushort* T = (ushort*)lds_all;
#pragma unroll
    for (int i = 0; i < 4; ++i)
#pragma unroll
      for (int j2 = 0; j2 < 4; ++j2) {
        const int gn_l = wc * 64 + j2 * 16 + (l & 15);
        const int gm_l = wr * 64 + i * 16 + ((l >> 4) << 2);
        const float bb = bias[n0 + gn_l];
        ushort4 u;
        u.x = __builtin_bit_cast(ushort, (__bf16)((acc[i][j2][0] + bb) * oscale));
        u.y = __builtin_bit_cast(ushort, (__bf16)((acc[i][j2][1] + bb) * oscale));
        u.z = __builtin_bit_cast(ushort, (__bf16)((acc[i][j2][2] + bb) * oscale));
        u.w = __builtin_bit_cast(ushort, (__bf16)((acc[i][j2][3] + bb) * oscale));
        *(ushort4*)(T + gn_l * 136 + gm_l) = u;
      }
    __syncthreads();
    const int gn_r = t >> 1, half = t & 1;
    const int hd_g = n0 + gn_r;
    const int hh = hd_g >> 6, hd = hd_g & 63;
    const int bb2 = m0 >> 11;
    const int s0 = (m0 & 2047) + half * 64;
    ushort* obase = (ushort*)Out +
                    (((size_t)(bb2 * 16 + hh) << 6) + hd) * 2048 + s0;
#pragma unroll
    for (int k2 = 0; k2 < 8; ++k2) {
      const int4 vd = *(const int4*)((const char*)T + (size_t)gn_r * 272 +
                                     half * 128 + k2 * 16);
      *(int4*)(obase + k2 * 8) = vd;
    }
  } else {
#pragma unroll
    for (int i = 0; i < 4; ++i)
#pragma unroll
      for (int j2 = 0; j2 < 4; ++j2)
#pragma unroll
        for (int rg = 0; rg < 4; ++rg) {
          const int gm = m0 + wr * 64 + i * 16 + ((l >> 4) << 2) + rg;
          const int gn = n0 + wc * 64 + j2 * 16 + (l & 15);
          const float v = (acc[i][j2][rg] + bias[gn]) * oscale;
          if constexpr (OMODE == 0) {
            const int b = gm >> 11, s = gm & 2047, h = gn >> 6, hd = gn & 63;
            ((ushort*)Out)[((((size_t)(b * 16 + h)) * 2048 + s) << 6) + hd] =
                __builtin_bit_cast(ushort, (__bf16)v);
          } else {
            ((float*)Out)[(size_t)gm * 1024 + gn] = v;
          }
        }
  }
#undef lAbuf
#undef lBbuf
}

// fallback GEMM (fp32 W, reg-staged, single-buffer) for small-ws path
template <int OMODE, int AM>
__global__ __launch_bounds__(256) void gemmF_k(const void* __restrict__ A,
                                               const float* __restrict__ Wf,
                                               const float* __restrict__ bias,
                                               void* __restrict__ Out,
                                               float oscale) {
  constexpr int K = 1024;
  __shared__ __align__(16) char lA[128 * 128];
  __shared__ __align__(16) char lB[128 * 128];
  const int t = threadIdx.x;
  const int l = t & 63;
  const int w = t >> 6;
  const int wr = w >> 1, wc = w & 1;
  const int m0 = blockIdx.x * 128;
  const int n0 = blockIdx.y * 128;
  f32x4 acc[4][4];
#pragma unroll
  for (int i = 0; i < 4; ++i)
#pragma unroll
    for (int j = 0; j < 4; ++j) acc[i][j] = (f32x4){0.f, 0.f, 0.f, 0.f};
  for (int k0 = 0; k0 < K; k0 += 64) {
#pragma unroll
    for (int qq = 0; qq < 4; ++qq) {
      const int L = t * 8 + qq * 2048;
      const int r = L >> 6, c = L & 63;
      const int dst = r * 128 + ((c * 2) ^ ((r & 7) << 4));
      if constexpr (AM == 0) {
        const float* s0 = (const float*)A + (size_t)(m0 + r) * K + k0 + c;
        *(int4*)(lA + dst) = cvt8(*(const float4*)s0, *(const float4*)(s0 + 4));
      } else {
        *(int4*)(lA + dst) =
            *(const int4*)((const ushort*)A + (size_t)(m0 + r) * K + k0 + c);
      }
      const float* s1 = Wf + (size_t)(n0 + r) * K + k0 + c;
      *(int4*)(lB + dst) = cvt8(*(const float4*)s1, *(const float4*)(s1 + 4));
    }
    __syncthreads();
#pragma unroll
    for (int ks = 0; ks < 2; ++ks) {
      const int kb = ks * 64 + ((l >> 4) << 4);
      bf16x8 af[4], bfv[4];
#pragma unroll
      for (int i = 0; i < 4; ++i) {
        const int row = wr * 64 + i * 16 + (l & 15);
        af[i] = *(const bf16x8*)(lA + row * 128 + (kb ^ ((row & 7) << 4)));
      }
#pragma unroll
      for (int j = 0; j < 4; ++j) {
        const int row = wc * 64 + j * 16 + (l & 15);
        bfv[j] = *(const bf16x8*)(lB + row * 128 + (kb ^ ((row & 7) << 4)));
      }
#pragma unroll
      for (int i = 0; i < 4; ++i)
#pragma unroll
        for (int j = 0; j < 4; ++j)
          acc[i][j] = __builtin_amdgcn_mfma_f32_16x16x32_bf16(af[i], bfv[j],
                                                              acc[i][j], 0, 0, 0);
    }
    __syncthreads();
  }
#pragma unroll
  for (int i = 0; i < 4; ++i)
#pragma unroll
    for (int j = 0; j < 4; ++j)
#pragma unroll
      for (int rg = 0; rg < 4; ++rg) {
        const int gm = m0 + wr * 64 + i * 16 + ((l >> 4) << 2) + rg;
        const int gn = n0 + wc * 64 + j * 16 + (l & 15);
        const float v = (acc[i][j][rg] + bias[gn]) * oscale;
        if constexpr (OMODE == 0) {
          const int b = gm >> 11, s = gm & 2047, h = gn >> 6, hd = gn & 63;
          ((ushort*)Out)[((((size_t)(b * 16 + h)) * 2048 + s) << 6) + hd] =
              __builtin_bit_cast(ushort, (__bf16)v);
        } else if constexpr (OMODE == 1) {
          const int b = gm >> 11, s = gm & 2047, h = gn >> 6, hd = gn & 63;
          ((ushort*)Out)[((((size_t)(b * 16 + h)) << 6) + hd) * 2048 + s] =
              __builtin_bit_cast(ushort, (__bf16)v);
        } else {
          ((float*)Out)[(size_t)gm * 1024 + gn] = v;
        }
      }
}

// Flash attention, causal. qh (PRE-SCALED by 0.125*log2e): [B,H,S,HD] bf16.
// kh: [B,H,S,HD] bf16. vth: [B,H,HD,S] bf16. out: [B,S,D] bf16.
// 256 thr = 4 waves x 32 q-rows (QBLK=128). CONSTANT-MAX softmax
// (p = 2^(s-8), constant cancels in O = acc/l).
// SPLIT=0: grid (64,16), one block per q-tile (r13/r15 structure, 61us).
// SPLIT=1: grid (64,24): qt>=8 split into 2 KV-halves (qt+1 tiles each);
//   halves store unnormalized fp32 acc + l to pacc/pl (plain vectorized
//   stores, deterministic); combine_k merges. Max block 16 tiles vs 32.
template <int SPLIT>
__global__ __launch_bounds__(256, 6) void attn_k(const ushort* __restrict__ qh,
                                                 const ushort* __restrict__ kh,
                                                 const ushort* __restrict__ vth,
                                                 ushort* __restrict__ out,
                                                 float* __restrict__ pacc,
                                                 float* __restrict__ pl) {
  const int bh = blockIdx.x;  // b*16 + h (fastest dim)
  int qt, t0, t1, half = 0;
  if constexpr (SPLIT) {
    const int y = blockIdx.y;
    if (y < 16) {  // split q-tiles, longest first
      qt = 15 - (y >> 1);
      half = y & 1;
      const int len = qt + 1;
      t0 = half * len;
      t1 = t0 + len;
    } else {
      qt = 23 - y;
      t0 = 0;
      t1 = 2 * qt + 2;
    }
  } else {
    qt = gridDim.y - 1 - blockIdx.y;  // longest tiles first
    t0 = 0;
    t1 = 2 * qt + 2;
  }
  const int q0 = qt * 128;
  const int t = threadIdx.x, l = t & 63, wv = t >> 6;
  const int lq = l & 31, hi = l >> 5;
  __shared__ __align__(16) char lk[2][64 * 128];
  __shared__ __align__(16) char lv[2][64 * 128];

  const int qrow = q0 + wv * 32 + lq;  // this lane's q (output col of S^T)
  bf16x8 qf0, qf1, qf2, qf3;
  {
    const ushort* qp = qh + ((size_t)bh * 2048 + qrow) * 64 + hi * 8;
    qf0 = *(const bf16x8*)(qp);
    qf1 = *(const bf16x8*)(qp + 16);
    qf2 = *(const bf16x8*)(qp + 32);
    qf3 = *(const bf16x8*)(qp + 48);
  }

  const int r0 = t >> 3;
  const int c0 = (t & 7) * 8;
  const ushort* kbase = kh + (size_t)bh * 2048 * 64 + (size_t)r0 * 64 + c0;
  const ushort* vbase = vth + (size_t)bh * 64 * 2048 + (size_t)r0 * 2048 + c0;
  const int dst0 = r0 * 128 + ((c0 * 2) ^ ((r0 & 7) << 4));

  int4 ka, kb2, va, vb2;  // named -> stay in VGPRs
#define LOAD_TILE(kv0)                                            \
  do {                                                            \
    ka  = *(const int4*)(kbase + (size_t)(kv0) * 64);             \
    kb2 = *(const int4*)(kbase + (size_t)(kv0) * 64 + 32 * 64);   \
    va  = *(const int4*)(vbase + (kv0));                          \
    vb2 = *(const int4*)(vbase + (kv0) + 32 * 2048);              \
  } while (0)
#define WRITE_TILE(buf)                                           \
  do {                                                            \
    *(int4*)(lk[buf] + dst0) = ka;                                \
    *(int4*)(lk[buf] + dst0 + 32 * 128) = kb2;                    \
    *(int4*)(lv[buf] + dst0) = va;                                \
    *(int4*)(lv[buf] + dst0 + 32 * 128) = vb2;                    \
  } while (0)

  LOAD_TILE(t0 << 6);
  WRITE_TILE(0);

  float l_r = 0.f;
  f32x16 acco[2];
#pragma unroll
  for (int dt = 0; dt < 2; ++dt)
#pragma unroll
    for (int r = 0; r < 16; ++r) acco[dt][r] = 0.f;

  int cur = 0;
#pragma unroll 1
  for (int ti = t0; ti < t1; ++ti) {
    __syncthreads();
    if (ti + 1 < t1) LOAD_TILE((ti + 1) << 6);

#pragma unroll
    for (int s = 0; s < 2; ++s) {
      const int kvs = (ti << 6) + s * 32;
      if (kvs > q0 + wv * 32 + 31) continue;  // wave-uniform: above diagonal

      // S^T[kv_local][q] = K_tile . Q^T  (4 k-steps over d=64)
      f32x16 p;
#pragma unroll
      for (int r = 0; r < 16; ++r) p[r] = 0.f;
      __builtin_amdgcn_s_setprio(1);
#pragma unroll
      for (int kd = 0; kd < 4; ++kd) {
        const int row = s * 32 + lq;
        const bf16x8 kf = *(const bf16x8*)(
            lk[cur] + row * 128 + ((kd * 32 + hi * 16) ^ ((row & 7) << 4)));
        const bf16x8 qf = (kd == 0) ? qf0 : (kd == 1) ? qf1 : (kd == 2) ? qf2 : qf3;
        p = mfma32(kf, qf, p);
      }
      __builtin_amdgcn_s_setprio(0);
      // causal mask: kv = kvs + (r&3) + 8*(r>>2) + 4*hi ; mask if kv > qrow
      if (kvs + 31 > q0 + wv * 32) {
#pragma unroll
        for (int r = 0; r < 16; ++r) {
          const int kv = kvs + (r & 3) + 8 * (r >> 2) + 4 * hi;
          if (kv > qrow) p[r] = -1e30f;
        }
      }
      // p = exp2(s - 8); constant shift cancels in O = acc / l
#pragma unroll
      for (int r = 0; r < 16; ++r) p[r] = __builtin_amdgcn_exp2f(p[r] - 8.0f);
      // row-sum tree
      float sr[8];
#pragma unroll
      for (int r = 0; r < 8; ++r) sr[r] = p[r] + p[r + 8];
#pragma unroll
      for (int r = 0; r < 4; ++r) sr[r] = sr[r] + sr[r + 4];
      float rs = (sr[0] + sr[1]) + (sr[2] + sr[3]);
      rs += __shfl_xor(rs, 32);
      l_r += rs;
      // pack P pairs: W[j][i] holds kv = 8j + 4hi + 2i + {0,1}
      unsigned W0a = pkbf(p[0], p[1]),   W0b = pkbf(p[2], p[3]);
      unsigned W1a = pkbf(p[4], p[5]),   W1b = pkbf(p[6], p[7]);
      unsigned W2a = pkbf(p[8], p[9]),   W2b = pkbf(p[10], p[11]);
      unsigned W3a = pkbf(p[12], p[13]), W3b = pkbf(p[14], p[15]);
      // PV: O^T += V^T . P  (2 k-steps of 16 kv)
#pragma unroll
      for (int ks = 0; ks < 2; ++ks) {
        unsigned a0u = ks ? W2a : W0a;
        unsigned a1u = ks ? W2b : W0b;
        unsigned b0u = ks ? W3a : W1a;
        unsigned b1u = ks ? W3b : W1b;
        plswap(a0u, b0u, hi);
        plswap(a1u, b1u, hi);
        const uint4 pw = {a0u, a1u, b0u, b1u};
        const bf16x8 pf = __builtin_bit_cast(bf16x8, pw);
        __builtin_amdgcn_s_setprio(1);
#pragma unroll
        for (int dt = 0; dt < 2; ++dt) {
          const int row = dt * 32 + lq;
          const bf16x8 vf = *(const bf16x8*)(
              lv[cur] + row * 128 +
              ((s * 64 + ks * 32 + hi * 16) ^ ((row & 7) << 4)));
          acco[dt] = mfma32(vf, pf, acco[dt]);
        }
        __builtin_amdgcn_s_setprio(0);
      }
    }
    if (ti + 1 < t1) WRITE_TILE(cur ^ 1);
    cur ^= 1;
  }
#undef LOAD_TILE
#undef WRITE_TILE
  // epilogue: lane = (q=qrow, d = (r&3)+8*(r>>2)+4*hi+32*dt)
  if constexpr (SPLIT) {
    if (blockIdx.y < 16) {  // split block: store unnormalized fp32 partials
      const int rowi = (bh << 10) | (qrow & 1023);  // qrow in [1024,2048)
      float* ab = pacc + (size_t)half * 4194304 + ((size_t)rowi << 6);
#pragma unroll
      for (int dt = 0; dt < 2; ++dt)
#pragma unroll
        for (int g = 0; g < 4; ++g) {
          float4 st;
          st.x = acco[dt][4 * g + 0];
          st.y = acco[dt][4 * g + 1];
          st.z = acco[dt][4 * g + 2];
          st.w = acco[dt][4 * g + 3];
          *(float4*)(ab + dt * 32 + g * 8 + hi * 4) = st;
        }
      pl[half * 65536 + rowi] = l_r;
      return;
    }
  }
  const int b = bh >> 4, h = bh & 15;
  const float inv = __builtin_amdgcn_rcpf(l_r);
  ushort* orow = out + ((size_t)(b * 2048 + qrow)) * 1024 + h * 64;
#pragma unroll
  for (int dt = 0; dt < 2; ++dt)
#pragma unroll
    for (int g = 0; g < 4; ++g) {
      ushort4 st;
      st.x = __builtin_bit_cast(ushort, (__bf16)(acco[dt][4 * g + 0] * inv));
      st.y = __builtin_bit_cast(ushort, (__bf16)(acco[dt][4 * g + 1] * inv));
      st.z = __builtin_bit_cast(ushort, (__bf16)(acco[dt][4 * g + 2] * inv));
      st.w = __builtin_bit_cast(ushort, (__bf16)(acco[dt][4 * g + 3] * inv));
      *(ushort4*)(orow + dt * 32 + g * 8 + hi * 4) = st;
    }
}

// combine split-KV partials: ao[q in 1024..2047] = (acc0+acc1)/(l0+l1), bf16.
// 524288 threads, 8 d-elems each.
__global__ __launch_bounds__(256) void combine_k(const float* __restrict__ pacc,
                                                 const float* __restrict__ pl,
                                                 ushort* __restrict__ out) {
  const int i = blockIdx.x * 256 + threadIdx.x;
  const int rowi = i >> 3;          // bh*1024 + qlocal
  const int dblk = (i & 7) * 8;
  const float* A0 = pacc + ((size_t)rowi << 6) + dblk;
  const float* A1 = A0 + 4194304;
  const float lsum = pl[rowi] + pl[rowi + 65536];
  const float inv = __builtin_amdgcn_rcpf(lsum);
  const float4 x0 = *(const float4*)A0;
  const float4 x1 = *(const float4*)(A0 + 4);
  const float4 y0 = *(const float4*)A1;
  const float4 y1 = *(const float4*)(A1 + 4);
  bf16x8 v;
  v[0] = (__bf16)((x0.x + y0.x) * inv);
  v[1] = (__bf16)((x0.y + y0.y) * inv);
  v[2] = (__bf16)((x0.z + y0.z) * inv);
  v[3] = (__bf16)((x0.w + y0.w) * inv);
  v[4] = (__bf16)((x1.x + y1.x) * inv);
  v[5] = (__bf16)((x1.y + y1.y) * inv);
  v[6] = (__bf16)((x1.z + y1.z) * inv);
  v[7] = (__bf16)((x1.w + y1.w) * inv);
  const int bh = rowi >> 10, q = (rowi & 1023) + 1024;
  const int b = bh >> 4, h = bh & 15;
  *(int4*)(out + ((size_t)(b * 2048 + q)) * 1024 + h * 64 + dblk) =
      __builtin_bit_cast(int4, v);
}

extern "C" void kernel_launch(void* const* d_in, const int* in_sizes, int n_in,
                              void* d_out, int out_size, void* d_ws, size_t ws_size,
                              hipStream_t stream) {
  (void)in_sizes; (void)n_in; (void)out_size;
  const float* query = (const float*)d_in[0];
  const float* key = (const float*)d_in[1];
  const float* value = (const float*)d_in[2];
  const float* Wq = (const float*)d_in[4];
  const float* bq = (const float*)d_in[5];
  const float* Wk = (const float*)d_in[6];
  const float* bk = (const float*)d_in[7];
  const float* Wv = (const float*)d_in[8];
  const float* bv = (const float*)d_in[9];
  const float* Wo = (const float*)d_in[10];
  const float* bo = (const float*)d_in[11];

  char* ws = (char*)d_ws;
  const size_t SZA = (size_t)8192 * 1024 * 2;
  const size_t SZW = (size_t)1024 * 1024 * 2;
  const size_t BASE = 4 * SZA + 4 * SZW;
  const size_t SZP = (size_t)2 * 4194304 * 4;   // 33.55 MB acc partials
  const size_t SZL = (size_t)2 * 65536 * 4;     // 0.52 MB l partials
  ushort* qh = (ushort*)(ws + 0 * SZA);
  ushort* kh = (ushort*)(ws + 1 * SZA);
  ushort* vt = (ushort*)(ws + 2 * SZA);
  ushort* ao = (ushort*)(ws + 3 * SZA);
  dim3 bb(256), gg(512), ba(256);
  const float QS = 0.125f * 1.44269504088896f;  // 1/sqrt(64) * log2(e)

  if (ws_size >= BASE) {
    ushort* wq = (ushort*)(ws + 4 * SZA);
    ushort* wk = (ushort*)(ws + 4 * SZA + 1 * SZW);
    ushort* wv = (ushort*)(ws + 4 * SZA + 2 * SZW);
    ushort* wo = (ushort*)(ws + 4 * SZA + 3 * SZW);
    const int n8w = 1024 * 1024 / 8;
    hipLaunchKernelGGL(cvt4_k, dim3(n8w / 256, 4), bb, 0, stream, Wq, Wk, Wv, Wo, wq, n8w);
    hipLaunchKernelGGL((gemm_k<0, 0>), gg, bb, 0, stream, (const void*)query, wq, bq, (void*)qh, QS);
    hipLaunchKernelGGL((gemm_k<0, 0>), gg, bb, 0, stream, (const void*)key, wk, bk, (void*)kh, 1.0f);
    hipLaunchKernelGGL((gemm_k<0, 3>), gg, bb, 0, stream, (const void*)value, wv, bv, (void*)vt, 1.0f);
    if (ws_size >= BASE + SZP + SZL) {
      float* pacc = (float*)(ws + BASE);
      float* pl = (float*)(ws + BASE + SZP);
      hipLaunchKernelGGL((attn_k<1>), dim3(64, 24), ba, 0, stream, qh, kh, vt, ao, pacc, pl);
      hipLaunchKernelGGL(combine_k, dim3(2048), bb, 0, stream, pacc, pl, ao);
    } else {
      hipLaunchKernelGGL((attn_k<0>), dim3(64, 16), ba, 0, stream, qh, kh, vt, ao,
                         (float*)nullptr, (float*)nullptr);
    }
    hipLaunchKernelGGL((gemm_k<1, 2>), gg, bb, 0, stream, (const void*)ao, wo, bo, d_out, 1.0f);
  } else {
    hipLaunchKernelGGL((gemmF_k<0, 0>), dim3(64, 8), bb, 0, stream, (const void*)query, Wq, bq, (void*)qh, QS);
    hipLaunchKernelGGL((gemmF_k<0, 0>), dim3(64, 8), bb, 0, stream, (const void*)key, Wk, bk, (void*)kh, 1.0f);
    hipLaunchKernelGGL((gemmF_k<1, 0>), dim3(64, 8), bb, 0, stream, (const void*)value, Wv, bv, (void*)vt, 1.0f);
    hipLaunchKernelGGL((attn_k<0>), dim3(64, 16), ba, 0, stream, qh, kh, vt, ao,
                       (float*)nullptr, (float*)nullptr);
    hipLaunchKernelGGL((gemmF_k<2, 1>), dim3(64, 8), bb, 0, stream, (const void*)ao, Wo, bo, d_out, 1.0f);
  }
}

// Round 17
// 167.542 us; speedup vs baseline: 1.0579x; 1.0579x over previous
//
#include <hip/hip_runtime.h>

typedef __bf16 bf16x8 __attribute__((ext_vector_type(8)));
typedef __bf16 bf16x2 __attribute__((ext_vector_type(2)));
typedef float f32x4 __attribute__((ext_vector_type(4)));
typedef float f32x16 __attribute__((ext_vector_type(16)));
typedef unsigned short ushort;

__device__ __forceinline__ int4 cvt8(float4 a, float4 b) {
  bf16x8 v;
  v[0] = (__bf16)a.x; v[1] = (__bf16)a.y; v[2] = (__bf16)a.z; v[3] = (__bf16)a.w;
  v[4] = (__bf16)b.x; v[5] = (__bf16)b.y; v[6] = (__bf16)b.z; v[7] = (__bf16)b.w;
  return __builtin_bit_cast(int4, v);
}

__device__ __forceinline__ void gld16(const void* g, void* l) {
  __builtin_amdgcn_global_load_lds(
      (const __attribute__((address_space(1))) void*)g,
      (__attribute__((address_space(3))) void*)l, 16, 0, 0);
}

// pack 2 f32 -> 1 dword of 2 bf16 (compiler emits v_cvt_pk_bf16_f32)
__device__ __forceinline__ unsigned pkbf(float a, float b) {
  bf16x2 v;
  v[0] = (__bf16)a;
  v[1] = (__bf16)b;
  return __builtin_bit_cast(unsigned, v);
}

// exchange: after call a = [a_lo | b_lo], b = [a_hi | b_hi] (32-lane halves)
#if __has_builtin(__builtin_amdgcn_permlane32_swap)
typedef unsigned u32x2 __attribute__((ext_vector_type(2)));
__device__ __forceinline__ void plswap(unsigned& a, unsigned& b, int hi) {
  (void)hi;
  u32x2 r = __builtin_amdgcn_permlane32_swap(a, b, false, false);
  a = r[0]; b = r[1];
}
#else
__device__ __forceinline__ void plswap(unsigned& a, unsigned& b, int hi) {
  const unsigned pa = (unsigned)__shfl_xor((int)a, 32);
  const unsigned pb = (unsigned)__shfl_xor((int)b, 32);
  const unsigned x = hi ? pb : a;
  const unsigned y = hi ? b : pa;
  a = x; b = y;
}
#endif

__device__ __forceinline__ f32x16 mfma32(bf16x8 a, bf16x8 b, f32x16 c) {
  return __builtin_amdgcn_mfma_f32_32x32x16_bf16(a, b, c, 0, 0, 0);
}

// 4 weight matrices fp32 -> bf16 in one launch (grid.y picks the matrix)
__global__ __launch_bounds__(256) void cvt4_k(const float* __restrict__ i0,
                                              const float* __restrict__ i1,
                                              const float* __restrict__ i2,
                                              const float* __restrict__ i3,
                                              ushort* __restrict__ o, int n8) {
  const int z = blockIdx.y;
  const float* in = (z == 0) ? i0 : (z == 1) ? i1 : (z == 2) ? i2 : i3;
  ushort* out = o + (size_t)z * 1024 * 1024;
  int i = blockIdx.x * 256 + threadIdx.x;
  if (i >= n8) return;
  const float4* p = (const float4*)in + (size_t)i * 2;
  *(int4*)(out + (size_t)i * 8) = cvt8(p[0], p[1]);
}

// C = (A @ W^T + bias) * oscale. M=8192, N=K=1024. Tile 128x128, BK=64.
// DOUBLE-BUFFERED (T14). XCD-aware 1D grid (512 blocks).
// AMODE 0: A fp32 (named-reg prefetch + cvt); 1: A bf16 (global_load_lds).
// OMODE 0: bf16 [B,H,S,HD]; 2: fp32 [M,N];
// OMODE 3: bf16 [B,H,HD,S] via LDS transpose (coalesced stores along S).
template <int AMODE, int OMODE>
__global__ __launch_bounds__(256) void gemm_k(const void* __restrict__ A,
                                              const ushort* __restrict__ W,
                                              const float* __restrict__ bias,
                                              void* __restrict__ Out,
                                              float oscale) {
  constexpr int K = 1024;
  __shared__ __align__(16) char lds_all[4][16384];  // lA = [0..1], lB = [2..3]
#define lAbuf(b) (lds_all[(b)])
#define lBbuf(b) (lds_all[2 + (b)])
  const int t = threadIdx.x;
  const int l = t & 63;
  const int w = t >> 6;
  const int wr = w >> 1, wc = w & 1;
  const int bid = blockIdx.x;
  const int xcd = bid & 7, j = bid >> 3;
  const int m0 = (xcd * 8 + (j >> 3)) * 128;
  const int n0 = (j & 7) * 128;
  const int srow = l >> 3;
  const int scol = ((l & 7) ^ srow) << 3;
  const int ar = t >> 3;
  const int ac = (t & 7) * 8;
  const float* Abase = (const float*)A + (size_t)(m0 + ar) * K + ac;
  const int adst = ar * 128 + ((ac * 2) ^ ((ar & 7) << 4));
  float4 a0, a1, a2, a3, a4, a5, a6, a7;  // named -> stay in VGPRs

#define LOAD_A(k0)                                         \
  do {                                                     \
    const float* ap = Abase + (k0);                        \
    a0 = *(const float4*)(ap);                             \
    a1 = *(const float4*)(ap + 4);                         \
    a2 = *(const float4*)(ap + 32 * K);                    \
    a3 = *(const float4*)(ap + 32 * K + 4);                \
    a4 = *(const float4*)(ap + 64 * K);                    \
    a5 = *(const float4*)(ap + 64 * K + 4);                \
    a6 = *(const float4*)(ap + 96 * K);                    \
    a7 = *(const float4*)(ap + 96 * K + 4);                \
  } while (0)
#define CVT_WRITE(b)                                       \
  do {                                                     \
    *(int4*)(lAbuf(b) + adst) = cvt8(a0, a1);              \
    *(int4*)(lAbuf(b) + adst + 32 * 128) = cvt8(a2, a3);   \
    *(int4*)(lAbuf(b) + adst + 64 * 128) = cvt8(a4, a5);   \
    *(int4*)(lAbuf(b) + adst + 96 * 128) = cvt8(a6, a7);   \
  } while (0)
#define GLD_A(k0, b)                                                        \
  do {                                                                      \
    _Pragma("unroll") for (int i = 0; i < 4; ++i) {                         \
      const int chunk = w * 4 + i;                                          \
      gld16((const ushort*)A + (size_t)(m0 + chunk * 8 + srow) * K + (k0) + \
                scol,                                                       \
            lAbuf(b) + chunk * 1024);                                       \
    }                                                                       \
  } while (0)
#define GLD_W(k0, b)                                                         \
  do {                                                                       \
    _Pragma("unroll") for (int i = 0; i < 4; ++i) {                          \
      const int chunk = w * 4 + i;                                           \
      gld16(W + (size_t)(n0 + chunk * 8 + srow) * K + (k0) + scol,           \
            lBbuf(b) + chunk * 1024);                                        \
    }                                                                        \
  } while (0)

  f32x4 acc[4][4];
#pragma unroll
  for (int i = 0; i < 4; ++i)
#pragma unroll
    for (int j2 = 0; j2 < 4; ++j2) acc[i][j2] = (f32x4){0.f, 0.f, 0.f, 0.f};

  if constexpr (AMODE == 0) {
    LOAD_A(0);
    CVT_WRITE(0);
  } else {
    GLD_A(0, 0);
  }
  GLD_W(0, 0);
  __syncthreads();

  int buf = 0;
  for (int k0 = 0; k0 < K; k0 += 64) {
    const int nk = k0 + 64;
    if (nk < K) {
      if constexpr (AMODE == 0) LOAD_A(nk);
      else GLD_A(nk, buf ^ 1);
      GLD_W(nk, buf ^ 1);
    }
#pragma unroll
    for (int ks = 0; ks < 2; ++ks) {
      const int kb = ks * 64 + ((l >> 4) << 4);
      bf16x8 af[4], bfv[4];
#pragma unroll
      for (int i = 0; i < 4; ++i) {
        const int row = wr * 64 + i * 16 + (l & 15);
        af[i] = *(const bf16x8*)(lAbuf(buf) + row * 128 + (kb ^ ((row & 7) << 4)));
      }
#pragma unroll
      for (int j2 = 0; j2 < 4; ++j2) {
        const int row = wc * 64 + j2 * 16 + (l & 15);
        bfv[j2] = *(const bf16x8*)(lBbuf(buf) + row * 128 + (kb ^ ((row & 7) << 4)));
      }
#pragma unroll
      for (int i = 0; i < 4; ++i)
#pragma unroll
        for (int j2 = 0; j2 < 4; ++j2)
          acc[i][j2] = __builtin_amdgcn_mfma_f32_16x16x32_bf16(af[i], bfv[j2],
                                                               acc[i][j2], 0, 0, 0);
    }
    if constexpr (AMODE == 0) {
      if (nk < K) CVT_WRITE(buf ^ 1);
    }
    __syncthreads();
    buf ^= 1;
  }
#undef LOAD_A
#undef CVT_WRITE
#undef GLD_A
#undef GLD_W

  if constexpr (OMODE == 3) {
    ushort* T = (ushort*)lds_all;
#pragma unroll
    for (int i = 0; i < 4; ++i)
#pragma unroll
      for (int j2 = 0; j2 < 4; ++j2) {
        const int gn_l = wc * 64 + j2 * 16 + (l & 15);
        const int gm_l = wr * 64 + i * 16 + ((l >> 4) << 2);
        const float bb = bias[n0 + gn_l];
        ushort4 u;
        u.x = __builtin_bit_cast(ushort, (__bf16)((acc[i][j2][0] + bb) * oscale));
        u.y = __builtin_bit_cast(ushort, (__bf16)((acc[i][j2][1] + bb) * oscale));
        u.z = __builtin_bit_cast(ushort, (__bf16)((acc[i][j2][2] + bb) * oscale));
        u.w = __builtin_bit_cast(ushort, (__bf16)((acc[i][j2][3] + bb) * oscale));
        *(ushort4*)(T + gn_l * 136 + gm_l) = u;
      }
    __syncthreads();
    const int gn_r = t >> 1, half = t & 1;
    const int hd_g = n0 + gn_r;
    const int hh = hd_g >> 6, hd = hd_g & 63;
    const int bb2 = m0 >> 11;
    const int s0 = (m0 & 2047) + half * 64;
    ushort* obase = (ushort*)Out +
                    (((size_t)(bb2 * 16 + hh) << 6) + hd) * 2048 + s0;
#pragma unroll
    for (int k2 = 0; k2 < 8; ++k2) {
      const int4 vd = *(const int4*)((const char*)T + (size_t)gn_r * 272 +
                                     half * 128 + k2 * 16);
      *(int4*)(obase + k2 * 8) = vd;
    }
  } else {
#pragma unroll
    for (int i = 0; i < 4; ++i)
#pragma unroll
      for (int j2 = 0; j2 < 4; ++j2)
#pragma unroll
        for (int rg = 0; rg < 4; ++rg) {
          const int gm = m0 + wr * 64 + i * 16 + ((l >> 4) << 2) + rg;
          const int gn = n0 + wc * 64 + j2 * 16 + (l & 15);
          const float v = (acc[i][j2][rg] + bias[gn]) * oscale;
          if constexpr (OMODE == 0) {
            const int b = gm >> 11, s = gm & 2047, h = gn >> 6, hd = gn & 63;
            ((ushort*)Out)[((((size_t)(b * 16 + h)) * 2048 + s) << 6) + hd] =
                __builtin_bit_cast(ushort, (__bf16)v);
          } else {
            ((float*)Out)[(size_t)gm * 1024 + gn] = v;
          }
        }
  }
#undef lAbuf
#undef lBbuf
}

// fallback GEMM (fp32 W, reg-staged, single-buffer) for small-ws path
template <int OMODE, int AM>
__global__ __launch_bounds__(256) void gemmF_k(const void* __restrict__ A,
                                               const float* __restrict__ Wf,
                                               const float* __restrict__ bias,
                                               void* __restrict__ Out,
                                               float oscale) {
  constexpr int K = 1024;
  __shared__ __align__(16) char lA[128 * 128];
  __shared__ __align__(16) char lB[128 * 128];
  const int t = threadIdx.x;
  const int l = t & 63;
  const int w = t >> 6;
  const int wr = w >> 1, wc = w & 1;
  const int m0 = blockIdx.x * 128;
  const int n0 = blockIdx.y * 128;
  f32x4 acc[4][4];
#pragma unroll
  for (int i = 0; i < 4; ++i)
#pragma unroll
    for (int j = 0; j < 4; ++j) acc[i][j] = (f32x4){0.f, 0.f, 0.f, 0.f};
  for (int k0 = 0; k0 < K; k0 += 64) {
#pragma unroll
    for (int qq = 0; qq < 4; ++qq) {
      const int L = t * 8 + qq * 2048;
      const int r = L >> 6, c = L & 63;
      const int dst = r * 128 + ((c * 2) ^ ((r & 7) << 4));
      if constexpr (AM == 0) {
        const float* s0 = (const float*)A + (size_t)(m0 + r) * K + k0 + c;
        *(int4*)(lA + dst) = cvt8(*(const float4*)s0, *(const float4*)(s0 + 4));
      } else {
        *(int4*)(lA + dst) =
            *(const int4*)((const ushort*)A + (size_t)(m0 + r) * K + k0 + c);
      }
      const float* s1 = Wf + (size_t)(n0 + r) * K + k0 + c;
      *(int4*)(lB + dst) = cvt8(*(const float4*)s1, *(const float4*)(s1 + 4));
    }
    __syncthreads();
#pragma unroll
    for (int ks = 0; ks < 2; ++ks) {
      const int kb = ks * 64 + ((l >> 4) << 4);
      bf16x8 af[4], bfv[4];
#pragma unroll
      for (int i = 0; i < 4; ++i) {
        const int row = wr * 64 + i * 16 + (l & 15);
        af[i] = *(const bf16x8*)(lA + row * 128 + (kb ^ ((row & 7) << 4)));
      }
#pragma unroll
      for (int j = 0; j < 4; ++j) {
        const int row = wc * 64 + j * 16 + (l & 15);
        bfv[j] = *(const bf16x8*)(lB + row * 128 + (kb ^ ((row & 7) << 4)));
      }
#pragma unroll
      for (int i = 0; i < 4; ++i)
#pragma unroll
        for (int j = 0; j < 4; ++j)
          acc[i][j] = __builtin_amdgcn_mfma_f32_16x16x32_bf16(af[i], bfv[j],
                                                              acc[i][j], 0, 0, 0);
    }
    __syncthreads();
  }
#pragma unroll
  for (int i = 0; i < 4; ++i)
#pragma unroll
    for (int j = 0; j < 4; ++j)
#pragma unroll
      for (int rg = 0; rg < 4; ++rg) {
        const int gm = m0 + wr * 64 + i * 16 + ((l >> 4) << 2) + rg;
        const int gn = n0 + wc * 64 + j * 16 + (l & 15);
        const float v = (acc[i][j][rg] + bias[gn]) * oscale;
        if constexpr (OMODE == 0) {
          const int b = gm >> 11, s = gm & 2047, h = gn >> 6, hd = gn & 63;
          ((ushort*)Out)[((((size_t)(b * 16 + h)) * 2048 + s) << 6) + hd] =
              __builtin_bit_cast(ushort, (__bf16)v);
        } else if constexpr (OMODE == 1) {
          const int b = gm >> 11, s = gm & 2047, h = gn >> 6, hd = gn & 63;
          ((ushort*)Out)[((((size_t)(b * 16 + h)) << 6) + hd) * 2048 + s] =
              __builtin_bit_cast(ushort, (__bf16)v);
        } else {
          ((float*)Out)[(size_t)gm * 1024 + gn] = v;
        }
      }
}

// Flash attention, causal. qh (PRE-SCALED by 0.125*log2e): [B,H,S,HD] bf16.
// kh: [B,H,S,HD] bf16. vth: [B,H,HD,S] bf16. out: [B,S,D] bf16.
// 256 thr = 4 waves x 32 q-rows (QBLK=128). CONSTANT-MAX softmax
// (p = 2^(s-8), constant cancels in O = acc/l). Wave-uniform diagonal skip.
// Lane-partial l accumulation; single cross-hi reduce in epilogue.
// VGPR pinned via __launch_bounds__(256,6). T5 setprio on MFMA clusters.
__global__ __launch_bounds__(256, 6) void attn_k(const ushort* __restrict__ qh,
                                                 const ushort* __restrict__ kh,
                                                 const ushort* __restrict__ vth,
                                                 ushort* __restrict__ out) {
  const int bh = blockIdx.x;                  // b*16 + h (fastest dim)
  const int qt = gridDim.y - 1 - blockIdx.y;  // longest tiles first
  const int q0 = qt * 128;
  const int t = threadIdx.x, l = t & 63, wv = t >> 6;
  const int lq = l & 31, hi = l >> 5;
  __shared__ __align__(16) char lk[2][64 * 128];
  __shared__ __align__(16) char lv[2][64 * 128];

  const int qrow = q0 + wv * 32 + lq;  // this lane's q (output col of S^T)
  bf16x8 qf0, qf1, qf2, qf3;
  {
    const ushort* qp = qh + ((size_t)bh * 2048 + qrow) * 64 + hi * 8;
    qf0 = *(const bf16x8*)(qp);
    qf1 = *(const bf16x8*)(qp + 16);
    qf2 = *(const bf16x8*)(qp + 32);
    qf3 = *(const bf16x8*)(qp + 48);
  }

  const int r0 = t >> 3;
  const int c0 = (t & 7) * 8;
  const ushort* kbase = kh + (size_t)bh * 2048 * 64 + (size_t)r0 * 64 + c0;
  const ushort* vbase = vth + (size_t)bh * 64 * 2048 + (size_t)r0 * 2048 + c0;
  const int dst0 = r0 * 128 + ((c0 * 2) ^ ((r0 & 7) << 4));

  int4 ka, kb2, va, vb2;  // named -> stay in VGPRs
#define LOAD_TILE(kv0)                                            \
  do {                                                            \
    ka  = *(const int4*)(kbase + (size_t)(kv0) * 64);             \
    kb2 = *(const int4*)(kbase + (size_t)(kv0) * 64 + 32 * 64);   \
    va  = *(const int4*)(vbase + (kv0));                          \
    vb2 = *(const int4*)(vbase + (kv0) + 32 * 2048);              \
  } while (0)
#define WRITE_TILE(buf)                                           \
  do {                                                            \
    *(int4*)(lk[buf] + dst0) = ka;                                \
    *(int4*)(lk[buf] + dst0 + 32 * 128) = kb2;                    \
    *(int4*)(lv[buf] + dst0) = va;                                \
    *(int4*)(lv[buf] + dst0 + 32 * 128) = vb2;                    \
  } while (0)

  LOAD_TILE(0);
  WRITE_TILE(0);

  float l_r = 0.f;  // lane-partial (own 16 kv-slots); cross-hi reduce at end
  f32x16 acco[2];
#pragma unroll
  for (int dt = 0; dt < 2; ++dt)
#pragma unroll
    for (int r = 0; r < 16; ++r) acco[dt][r] = 0.f;

  const int nt = 2 * qt + 2;  // staged 64-wide KV tiles
  int cur = 0;
#pragma unroll 1
  for (int ti = 0; ti < nt; ++ti) {
    __syncthreads();
    if (ti + 1 < nt) LOAD_TILE((ti + 1) << 6);

#pragma unroll
    for (int s = 0; s < 2; ++s) {
      const int kvs = (ti << 6) + s * 32;
      if (kvs > q0 + wv * 32 + 31) continue;  // wave-uniform: above diagonal

      // S^T[kv_local][q] = K_tile . Q^T  (4 k-steps over d=64)
      f32x16 p;
#pragma unroll
      for (int r = 0; r < 16; ++r) p[r] = 0.f;
      __builtin_amdgcn_s_setprio(1);
#pragma unroll
      for (int kd = 0; kd < 4; ++kd) {
        const int row = s * 32 + lq;
        const bf16x8 kf = *(const bf16x8*)(
            lk[cur] + row * 128 + ((kd * 32 + hi * 16) ^ ((row & 7) << 4)));
        const bf16x8 qf = (kd == 0) ? qf0 : (kd == 1) ? qf1 : (kd == 2) ? qf2 : qf3;
        p = mfma32(kf, qf, p);
      }
      __builtin_amdgcn_s_setprio(0);
      // causal mask: kv = kvs + (r&3) + 8*(r>>2) + 4*hi ; mask if kv > qrow
      if (kvs + 31 > q0 + wv * 32) {
#pragma unroll
        for (int r = 0; r < 16; ++r) {
          const int kv = kvs + (r & 3) + 8 * (r >> 2) + 4 * hi;
          if (kv > qrow) p[r] = -1e30f;
        }
      }
      // p = exp2(s - 8); constant shift cancels in O = acc / l
#pragma unroll
      for (int r = 0; r < 16; ++r) p[r] = __builtin_amdgcn_exp2f(p[r] - 8.0f);
      // lane-partial row-sum tree (cross-hi deferred to epilogue)
      float sr[8];
#pragma unroll
      for (int r = 0; r < 8; ++r) sr[r] = p[r] + p[r + 8];
#pragma unroll
      for (int r = 0; r < 4; ++r) sr[r] = sr[r] + sr[r + 4];
      l_r += (sr[0] + sr[1]) + (sr[2] + sr[3]);
      // pack P pairs: W[j][i] holds kv = 8j + 4hi + 2i + {0,1}
      unsigned W0a = pkbf(p[0], p[1]),   W0b = pkbf(p[2], p[3]);
      unsigned W1a = pkbf(p[4], p[5]),   W1b = pkbf(p[6], p[7]);
      unsigned W2a = pkbf(p[8], p[9]),   W2b = pkbf(p[10], p[11]);
      unsigned W3a = pkbf(p[12], p[13]), W3b = pkbf(p[14], p[15]);
      // PV: O^T += V^T . P  (2 k-steps of 16 kv)
#pragma unroll
      for (int ks = 0; ks < 2; ++ks) {
        unsigned a0u = ks ? W2a : W0a;
        unsigned a1u = ks ? W2b : W0b;
        unsigned b0u = ks ? W3a : W1a;
        unsigned b1u = ks ? W3b : W1b;
        plswap(a0u, b0u, hi);
        plswap(a1u, b1u, hi);
        const uint4 pw = {a0u, a1u, b0u, b1u};
        const bf16x8 pf = __builtin_bit_cast(bf16x8, pw);
        __builtin_amdgcn_s_setprio(1);
#pragma unroll
        for (int dt = 0; dt < 2; ++dt) {
          const int row = dt * 32 + lq;
          const bf16x8 vf = *(const bf16x8*)(
              lv[cur] + row * 128 +
              ((s * 64 + ks * 32 + hi * 16) ^ ((row & 7) << 4)));
          acco[dt] = mfma32(vf, pf, acco[dt]);
        }
        __builtin_amdgcn_s_setprio(0);
      }
    }
    if (ti + 1 < nt) WRITE_TILE(cur ^ 1);
    cur ^= 1;
  }
#undef LOAD_TILE
#undef WRITE_TILE
  // epilogue: lane = (q=qrow, d = (r&3)+8*(r>>2)+4*hi+32*dt)
  l_r += __shfl_xor(l_r, 32);  // combine hi-halves (disjoint kv slots)
  const int b = bh >> 4, h = bh & 15;
  const float inv = __builtin_amdgcn_rcpf(l_r);
  ushort* orow = out + ((size_t)(b * 2048 + qrow)) * 1024 + h * 64;
#pragma unroll
  for (int dt = 0; dt < 2; ++dt)
#pragma unroll
    for (int g = 0; g < 4; ++g) {
      ushort4 st;
      st.x = __builtin_bit_cast(ushort, (__bf16)(acco[dt][4 * g + 0] * inv));
      st.y = __builtin_bit_cast(ushort, (__bf16)(acco[dt][4 * g + 1] * inv));
      st.z = __builtin_bit_cast(ushort, (__bf16)(acco[dt][4 * g + 2] * inv));
      st.w = __builtin_bit_cast(ushort, (__bf16)(acco[dt][4 * g + 3] * inv));
      *(ushort4*)(orow + dt * 32 + g * 8 + hi * 4) = st;
    }
}

extern "C" void kernel_launch(void* const* d_in, const int* in_sizes, int n_in,
                              void* d_out, int out_size, void* d_ws, size_t ws_size,
                              hipStream_t stream) {
  (void)in_sizes; (void)n_in; (void)out_size;
  const float* query = (const float*)d_in[0];
  const float* key = (const float*)d_in[1];
  const float* value = (const float*)d_in[2];
  const float* Wq = (const float*)d_in[4];
  const float* bq = (const float*)d_in[5];
  const float* Wk = (const float*)d_in[6];
  const float* bk = (const float*)d_in[7];
  const float* Wv = (const float*)d_in[8];
  const float* bv = (const float*)d_in[9];
  const float* Wo = (const float*)d_in[10];
  const float* bo = (const float*)d_in[11];

  char* ws = (char*)d_ws;
  const size_t SZA = (size_t)8192 * 1024 * 2;
  const size_t SZW = (size_t)1024 * 1024 * 2;
  ushort* qh = (ushort*)(ws + 0 * SZA);
  ushort* kh = (ushort*)(ws + 1 * SZA);
  ushort* vt = (ushort*)(ws + 2 * SZA);
  ushort* ao = (ushort*)(ws + 3 * SZA);
  dim3 bb(256), gg(512), ga(64, 16), ba(256);
  const float QS = 0.125f * 1.44269504088896f;  // 1/sqrt(64) * log2(e)

  if (ws_size >= 4 * SZA + 4 * SZW) {
    ushort* wq = (ushort*)(ws + 4 * SZA);
    ushort* wk = (ushort*)(ws + 4 * SZA + 1 * SZW);
    ushort* wv = (ushort*)(ws + 4 * SZA + 2 * SZW);
    ushort* wo = (ushort*)(ws + 4 * SZA + 3 * SZW);
    const int n8w = 1024 * 1024 / 8;
    hipLaunchKernelGGL(cvt4_k, dim3(n8w / 256, 4), bb, 0, stream, Wq, Wk, Wv, Wo, wq, n8w);
    hipLaunchKernelGGL((gemm_k<0, 0>), gg, bb, 0, stream, (const void*)query, wq, bq, (void*)qh, QS);
    hipLaunchKernelGGL((gemm_k<0, 0>), gg, bb, 0, stream, (const void*)key, wk, bk, (void*)kh, 1.0f);
    hipLaunchKernelGGL((gemm_k<0, 3>), gg, bb, 0, stream, (const void*)value, wv, bv, (void*)vt, 1.0f);
    hipLaunchKernelGGL(attn_k, ga, ba, 0, stream, qh, kh, vt, ao);
    hipLaunchKernelGGL((gemm_k<1, 2>), gg, bb, 0, stream, (const void*)ao, wo, bo, d_out, 1.0f);
  } else {
    hipLaunchKernelGGL((gemmF_k<0, 0>), dim3(64, 8), bb, 0, stream, (const void*)query, Wq, bq, (void*)qh, QS);
    hipLaunchKernelGGL((gemmF_k<0, 0>), dim3(64, 8), bb, 0, stream, (const void*)key, Wk, bk, (void*)kh, 1.0f);
    hipLaunchKernelGGL((gemmF_k<1, 0>), dim3(64, 8), bb, 0, stream, (const void*)value, Wv, bv, (void*)vt, 1.0f);
    hipLaunchKernelGGL(attn_k, ga, ba, 0, stream, qh, kh, vt, ao);
    hipLaunchKernelGGL((gemmF_k<2, 1>), dim3(64, 8), bb, 0, stream, (const void*)ao, Wo, bo, d_out, 1.0f);
  }
}

// Round 18
// 166.897 us; speedup vs baseline: 1.0620x; 1.0039x over previous
//
#include <hip/hip_runtime.h>

typedef __bf16 bf16x8 __attribute__((ext_vector_type(8)));
typedef __bf16 bf16x2 __attribute__((ext_vector_type(2)));
typedef float f32x4 __attribute__((ext_vector_type(4)));
typedef float f32x16 __attribute__((ext_vector_type(16)));
typedef unsigned short ushort;

__device__ __forceinline__ int4 cvt8(float4 a, float4 b) {
  bf16x8 v;
  v[0] = (__bf16)a.x; v[1] = (__bf16)a.y; v[2] = (__bf16)a.z; v[3] = (__bf16)a.w;
  v[4] = (__bf16)b.x; v[5] = (__bf16)b.y; v[6] = (__bf16)b.z; v[7] = (__bf16)b.w;
  return __builtin_bit_cast(int4, v);
}

__device__ __forceinline__ void gld16(const void* g, void* l) {
  __builtin_amdgcn_global_load_lds(
      (const __attribute__((address_space(1))) void*)g,
      (__attribute__((address_space(3))) void*)l, 16, 0, 0);
}

// pack 2 f32 -> 1 dword of 2 bf16 (compiler emits v_cvt_pk_bf16_f32)
__device__ __forceinline__ unsigned pkbf(float a, float b) {
  bf16x2 v;
  v[0] = (__bf16)a;
  v[1] = (__bf16)b;
  return __builtin_bit_cast(unsigned, v);
}

// exchange: after call a = [a_lo | b_lo], b = [a_hi | b_hi] (32-lane halves)
#if __has_builtin(__builtin_amdgcn_permlane32_swap)
typedef unsigned u32x2 __attribute__((ext_vector_type(2)));
__device__ __forceinline__ void plswap(unsigned& a, unsigned& b, int hi) {
  (void)hi;
  u32x2 r = __builtin_amdgcn_permlane32_swap(a, b, false, false);
  a = r[0]; b = r[1];
}
#else
__device__ __forceinline__ void plswap(unsigned& a, unsigned& b, int hi) {
  const unsigned pa = (unsigned)__shfl_xor((int)a, 32);
  const unsigned pb = (unsigned)__shfl_xor((int)b, 32);
  const unsigned x = hi ? pb : a;
  const unsigned y = hi ? b : pa;
  a = x; b = y;
}
#endif

__device__ __forceinline__ f32x16 mfma32(bf16x8 a, bf16x8 b, f32x16 c) {
  return __builtin_amdgcn_mfma_f32_32x32x16_bf16(a, b, c, 0, 0, 0);
}

// 4 weight matrices fp32 -> bf16 in one launch (grid.y picks the matrix)
__global__ __launch_bounds__(256) void cvt4_k(const float* __restrict__ i0,
                                              const float* __restrict__ i1,
                                              const float* __restrict__ i2,
                                              const float* __restrict__ i3,
                                              ushort* __restrict__ o, int n8) {
  const int z = blockIdx.y;
  const float* in = (z == 0) ? i0 : (z == 1) ? i1 : (z == 2) ? i2 : i3;
  ushort* out = o + (size_t)z * 1024 * 1024;
  int i = blockIdx.x * 256 + threadIdx.x;
  if (i >= n8) return;
  const float4* p = (const float4*)in + (size_t)i * 2;
  *(int4*)(out + (size_t)i * 8) = cvt8(p[0], p[1]);
}

// C = (A @ W^T + bias) * oscale. M=8192, N=K=1024. Tile 128x128, BK=64.
// DOUBLE-BUFFERED (T14). XCD-aware 1D grid (512 blocks).
// AMODE 0: A fp32 (named-reg prefetch + cvt); 1: A bf16 (global_load_lds).
// OMODE 0: bf16 [B,H,S,HD]; 2: fp32 [M,N];
// OMODE 3: bf16 [B,H,HD,S] via LDS transpose (coalesced stores along S).
template <int AMODE, int OMODE>
__global__ __launch_bounds__(256) void gemm_k(const void* __restrict__ A,
                                              const ushort* __restrict__ W,
                                              const float* __restrict__ bias,
                                              void* __restrict__ Out,
                                              float oscale) {
  constexpr int K = 1024;
  __shared__ __align__(16) char lds_all[4][16384];  // lA = [0..1], lB = [2..3]
#define lAbuf(b) (lds_all[(b)])
#define lBbuf(b) (lds_all[2 + (b)])
  const int t = threadIdx.x;
  const int l = t & 63;
  const int w = t >> 6;
  const int wr = w >> 1, wc = w & 1;
  const int bid = blockIdx.x;
  const int xcd = bid & 7, j = bid >> 3;
  const int m0 = (xcd * 8 + (j >> 3)) * 128;
  const int n0 = (j & 7) * 128;
  const int srow = l >> 3;
  const int scol = ((l & 7) ^ srow) << 3;
  const int ar = t >> 3;
  const int ac = (t & 7) * 8;
  const float* Abase = (const float*)A + (size_t)(m0 + ar) * K + ac;
  const int adst = ar * 128 + ((ac * 2) ^ ((ar & 7) << 4));
  float4 a0, a1, a2, a3, a4, a5, a6, a7;  // named -> stay in VGPRs

#define LOAD_A(k0)                                         \
  do {                                                     \
    const float* ap = Abase + (k0);                        \
    a0 = *(const float4*)(ap);                             \
    a1 = *(const float4*)(ap + 4);                         \
    a2 = *(const float4*)(ap + 32 * K);                    \
    a3 = *(const float4*)(ap + 32 * K + 4);                \
    a4 = *(const float4*)(ap + 64 * K);                    \
    a5 = *(const float4*)(ap + 64 * K + 4);                \
    a6 = *(const float4*)(ap + 96 * K);                    \
    a7 = *(const float4*)(ap + 96 * K + 4);                \
  } while (0)
#define CVT_WRITE(b)                                       \
  do {                                                     \
    *(int4*)(lAbuf(b) + adst) = cvt8(a0, a1);              \
    *(int4*)(lAbuf(b) + adst + 32 * 128) = cvt8(a2, a3);   \
    *(int4*)(lAbuf(b) + adst + 64 * 128) = cvt8(a4, a5);   \
    *(int4*)(lAbuf(b) + adst + 96 * 128) = cvt8(a6, a7);   \
  } while (0)
#define GLD_A(k0, b)                                                        \
  do {                                                                      \
    _Pragma("unroll") for (int i = 0; i < 4; ++i) {                         \
      const int chunk = w * 4 + i;                                          \
      gld16((const ushort*)A + (size_t)(m0 + chunk * 8 + srow) * K + (k0) + \
                scol,                                                       \
            lAbuf(b) + chunk * 1024);                                       \
    }                                                                       \
  } while (0)
#define GLD_W(k0, b)                                                         \
  do {                                                                       \
    _Pragma("unroll") for (int i = 0; i < 4; ++i) {                          \
      const int chunk = w * 4 + i;                                           \
      gld16(W + (size_t)(n0 + chunk * 8 + srow) * K + (k0) + scol,           \
            lBbuf(b) + chunk * 1024);                                        \
    }                                                                        \
  } while (0)

  f32x4 acc[4][4];
#pragma unroll
  for (int i = 0; i < 4; ++i)
#pragma unroll
    for (int j2 = 0; j2 < 4; ++j2) acc[i][j2] = (f32x4){0.f, 0.f, 0.f, 0.f};

  if constexpr (AMODE == 0) {
    LOAD_A(0);
    CVT_WRITE(0);
  } else {
    GLD_A(0, 0);
  }
  GLD_W(0, 0);
  __syncthreads();

  int buf = 0;
  for (int k0 = 0; k0 < K; k0 += 64) {
    const int nk = k0 + 64;
    if (nk < K) {
      if constexpr (AMODE == 0) LOAD_A(nk);
      else GLD_A(nk, buf ^ 1);
      GLD_W(nk, buf ^ 1);
    }
#pragma unroll
    for (int ks = 0; ks < 2; ++ks) {
      const int kb = ks * 64 + ((l >> 4) << 4);
      bf16x8 af[4], bfv[4];
#pragma unroll
      for (int i = 0; i < 4; ++i) {
        const int row = wr * 64 + i * 16 + (l & 15);
        af[i] = *(const bf16x8*)(lAbuf(buf) + row * 128 + (kb ^ ((row & 7) << 4)));
      }
#pragma unroll
      for (int j2 = 0; j2 < 4; ++j2) {
        const int row = wc * 64 + j2 * 16 + (l & 15);
        bfv[j2] = *(const bf16x8*)(lBbuf(buf) + row * 128 + (kb ^ ((row & 7) << 4)));
      }
#pragma unroll
      for (int i = 0; i < 4; ++i)
#pragma unroll
        for (int j2 = 0; j2 < 4; ++j2)
          acc[i][j2] = __builtin_amdgcn_mfma_f32_16x16x32_bf16(af[i], bfv[j2],
                                                               acc[i][j2], 0, 0, 0);
    }
    if constexpr (AMODE == 0) {
      if (nk < K) CVT_WRITE(buf ^ 1);
    }
    __syncthreads();
    buf ^= 1;
  }
#undef LOAD_A
#undef CVT_WRITE
#undef GLD_A
#undef GLD_W

  if constexpr (OMODE == 3) {
    ushort* T = (ushort*)lds_all;
#pragma unroll
    for (int i = 0; i < 4; ++i)
#pragma unroll
      for (int j2 = 0; j2 < 4; ++j2) {
        const int gn_l = wc * 64 + j2 * 16 + (l & 15);
        const int gm_l = wr * 64 + i * 16 + ((l >> 4) << 2);
        const float bb = bias[n0 + gn_l];
        ushort4 u;
        u.x = __builtin_bit_cast(ushort, (__bf16)((acc[i][j2][0] + bb) * oscale));
        u.y = __builtin_bit_cast(ushort, (__bf16)((acc[i][j2][1] + bb) * oscale));
        u.z = __builtin_bit_cast(ushort, (__bf16)((acc[i][j2][2] + bb) * oscale));
        u.w = __builtin_bit_cast(ushort, (__bf16)((acc[i][j2][3] + bb) * oscale));
        *(ushort4*)(T + gn_l * 136 + gm_l) = u;
      }
    __syncthreads();
    const int gn_r = t >> 1, half = t & 1;
    const int hd_g = n0 + gn_r;
    const int hh = hd_g >> 6, hd = hd_g & 63;
    const int bb2 = m0 >> 11;
    const int s0 = (m0 & 2047) + half * 64;
    ushort* obase = (ushort*)Out +
                    (((size_t)(bb2 * 16 + hh) << 6) + hd) * 2048 + s0;
#pragma unroll
    for (int k2 = 0; k2 < 8; ++k2) {
      const int4 vd = *(const int4*)((const char*)T + (size_t)gn_r * 272 +
                                     half * 128 + k2 * 16);
      *(int4*)(obase + k2 * 8) = vd;
    }
  } else {
#pragma unroll
    for (int i = 0; i < 4; ++i)
#pragma unroll
      for (int j2 = 0; j2 < 4; ++j2)
#pragma unroll
        for (int rg = 0; rg < 4; ++rg) {
          const int gm = m0 + wr * 64 + i * 16 + ((l >> 4) << 2) + rg;
          const int gn = n0 + wc * 64 + j2 * 16 + (l & 15);
          const float v = (acc[i][j2][rg] + bias[gn]) * oscale;
          if constexpr (OMODE == 0) {
            const int b = gm >> 11, s = gm & 2047, h = gn >> 6, hd = gn & 63;
            ((ushort*)Out)[((((size_t)(b * 16 + h)) * 2048 + s) << 6) + hd] =
                __builtin_bit_cast(ushort, (__bf16)v);
          } else {
            ((float*)Out)[(size_t)gm * 1024 + gn] = v;
          }
        }
  }
#undef lAbuf
#undef lBbuf
}

// fallback GEMM (fp32 W, reg-staged, single-buffer) for small-ws path
template <int OMODE, int AM>
__global__ __launch_bounds__(256) void gemmF_k(const void* __restrict__ A,
                                               const float* __restrict__ Wf,
                                               const float* __restrict__ bias,
                                               void* __restrict__ Out,
                                               float oscale) {
  constexpr int K = 1024;
  __shared__ __align__(16) char lA[128 * 128];
  __shared__ __align__(16) char lB[128 * 128];
  const int t = threadIdx.x;
  const int l = t & 63;
  const int w = t >> 6;
  const int wr = w >> 1, wc = w & 1;
  const int m0 = blockIdx.x * 128;
  const int n0 = blockIdx.y * 128;
  f32x4 acc[4][4];
#pragma unroll
  for (int i = 0; i < 4; ++i)
#pragma unroll
    for (int j = 0; j < 4; ++j) acc[i][j] = (f32x4){0.f, 0.f, 0.f, 0.f};
  for (int k0 = 0; k0 < K; k0 += 64) {
#pragma unroll
    for (int qq = 0; qq < 4; ++qq) {
      const int L = t * 8 + qq * 2048;
      const int r = L >> 6, c = L & 63;
      const int dst = r * 128 + ((c * 2) ^ ((r & 7) << 4));
      if constexpr (AM == 0) {
        const float* s0 = (const float*)A + (size_t)(m0 + r) * K + k0 + c;
        *(int4*)(lA + dst) = cvt8(*(const float4*)s0, *(const float4*)(s0 + 4));
      } else {
        *(int4*)(lA + dst) =
            *(const int4*)((const ushort*)A + (size_t)(m0 + r) * K + k0 + c);
      }
      const float* s1 = Wf + (size_t)(n0 + r) * K + k0 + c;
      *(int4*)(lB + dst) = cvt8(*(const float4*)s1, *(const float4*)(s1 + 4));
    }
    __syncthreads();
#pragma unroll
    for (int ks = 0; ks < 2; ++ks) {
      const int kb = ks * 64 + ((l >> 4) << 4);
      bf16x8 af[4], bfv[4];
#pragma unroll
      for (int i = 0; i < 4; ++i) {
        const int row = wr * 64 + i * 16 + (l & 15);
        af[i] = *(const bf16x8*)(lA + row * 128 + (kb ^ ((row & 7) << 4)));
      }
#pragma unroll
      for (int j = 0; j < 4; ++j) {
        const int row = wc * 64 + j * 16 + (l & 15);
        bfv[j] = *(const bf16x8*)(lB + row * 128 + (kb ^ ((row & 7) << 4)));
      }
#pragma unroll
      for (int i = 0; i < 4; ++i)
#pragma unroll
        for (int j = 0; j < 4; ++j)
          acc[i][j] = __builtin_amdgcn_mfma_f32_16x16x32_bf16(af[i], bfv[j],
                                                              acc[i][j], 0, 0, 0);
    }
    __syncthreads();
  }
#pragma unroll
  for (int i = 0; i < 4; ++i)
#pragma unroll
    for (int j = 0; j < 4; ++j)
#pragma unroll
      for (int rg = 0; rg < 4; ++rg) {
        const int gm = m0 + wr * 64 + i * 16 + ((l >> 4) << 2) + rg;
        const int gn = n0 + wc * 64 + j * 16 + (l & 15);
        const float v = (acc[i][j][rg] + bias[gn]) * oscale;
        if constexpr (OMODE == 0) {
          const int b = gm >> 11, s = gm & 2047, h = gn >> 6, hd = gn & 63;
          ((ushort*)Out)[((((size_t)(b * 16 + h)) * 2048 + s) << 6) + hd] =
              __builtin_bit_cast(ushort, (__bf16)v);
        } else if constexpr (OMODE == 1) {
          const int b = gm >> 11, s = gm & 2047, h = gn >> 6, hd = gn & 63;
          ((ushort*)Out)[((((size_t)(b * 16 + h)) << 6) + hd) * 2048 + s] =
              __builtin_bit_cast(ushort, (__bf16)v);
        } else {
          ((float*)Out)[(size_t)gm * 1024 + gn] = v;
        }
      }
}

// Flash attention, causal. qh (PRE-SCALED by 0.125*log2e): [B,H,S,HD] bf16.
// kh: [B,H,S,HD] bf16. vth: [B,H,HD,S] bf16. out: [B,S,D] bf16.
// 256 thr = 4 waves x 32 q-rows (QBLK=128). CONSTANT-MAX softmax
// (p = 2^s, normalization cancels in O = acc/l; |s| <= ~20 so no overflow).
// CU-balanced q-tile permutation: qt = P[y] with per-CU-group sums equal
// (P = 15,13,11,9, 0,2,4,6, 14,12,10,8, 1,3,5,7 -- groups {y,y+4,y+8,y+12}
// each sum to 30). Lane-partial l; single cross-hi reduce in epilogue.
// VGPR pinned via __launch_bounds__(256,6). T5 setprio on MFMA clusters.
__global__ __launch_bounds__(256, 6) void attn_k(const ushort* __restrict__ qh,
                                                 const ushort* __restrict__ kh,
                                                 const ushort* __restrict__ vth,
                                                 ushort* __restrict__ out) {
  const int bh = blockIdx.x;  // b*16 + h (fastest dim)
  const int y = blockIdx.y;
  const int g = y >> 2, r4 = y & 3;
  // P: g=0 -> 15-2r; g=1 -> 2r; g=2 -> 14-2r; g=3 -> 2r+1
  const int qt = (g & 1) ? (2 * r4 + (g >> 1)) : (((g == 0) ? 15 : 14) - 2 * r4);
  const int q0 = qt * 128;
  const int t = threadIdx.x, l = t & 63, wv = t >> 6;
  const int lq = l & 31, hi = l >> 5;
  __shared__ __align__(16) char lk[2][64 * 128];
  __shared__ __align__(16) char lv[2][64 * 128];

  const int qrow = q0 + wv * 32 + lq;  // this lane's q (output col of S^T)
  bf16x8 qf0, qf1, qf2, qf3;
  {
    const ushort* qp = qh + ((size_t)bh * 2048 + qrow) * 64 + hi * 8;
    qf0 = *(const bf16x8*)(qp);
    qf1 = *(const bf16x8*)(qp + 16);
    qf2 = *(const bf16x8*)(qp + 32);
    qf3 = *(const bf16x8*)(qp + 48);
  }

  const int r0 = t >> 3;
  const int c0 = (t & 7) * 8;
  const ushort* kbase = kh + (size_t)bh * 2048 * 64 + (size_t)r0 * 64 + c0;
  const ushort* vbase = vth + (size_t)bh * 64 * 2048 + (size_t)r0 * 2048 + c0;
  const int dst0 = r0 * 128 + ((c0 * 2) ^ ((r0 & 7) << 4));

  int4 ka, kb2, va, vb2;  // named -> stay in VGPRs
#define LOAD_TILE(kv0)                                            \
  do {                                                            \
    ka  = *(const int4*)(kbase + (size_t)(kv0) * 64);             \
    kb2 = *(const int4*)(kbase + (size_t)(kv0) * 64 + 32 * 64);   \
    va  = *(const int4*)(vbase + (kv0));                          \
    vb2 = *(const int4*)(vbase + (kv0) + 32 * 2048);              \
  } while (0)
#define WRITE_TILE(buf)                                           \
  do {                                                            \
    *(int4*)(lk[buf] + dst0) = ka;                                \
    *(int4*)(lk[buf] + dst0 + 32 * 128) = kb2;                    \
    *(int4*)(lv[buf] + dst0) = va;                                \
    *(int4*)(lv[buf] + dst0 + 32 * 128) = vb2;                    \
  } while (0)

  LOAD_TILE(0);
  WRITE_TILE(0);

  float l_r = 0.f;  // lane-partial (own 16 kv-slots); cross-hi reduce at end
  f32x16 acco[2];
#pragma unroll
  for (int dt = 0; dt < 2; ++dt)
#pragma unroll
    for (int r = 0; r < 16; ++r) acco[dt][r] = 0.f;

  const int nt = 2 * qt + 2;  // staged 64-wide KV tiles
  int cur = 0;
#pragma unroll 1
  for (int ti = 0; ti < nt; ++ti) {
    __syncthreads();
    if (ti + 1 < nt) LOAD_TILE((ti + 1) << 6);

#pragma unroll
    for (int s = 0; s < 2; ++s) {
      const int kvs = (ti << 6) + s * 32;
      if (kvs > q0 + wv * 32 + 31) continue;  // wave-uniform: above diagonal

      // S^T[kv_local][q] = K_tile . Q^T  (4 k-steps over d=64)
      f32x16 p;
#pragma unroll
      for (int r = 0; r < 16; ++r) p[r] = 0.f;
      __builtin_amdgcn_s_setprio(1);
#pragma unroll
      for (int kd = 0; kd < 4; ++kd) {
        const int row = s * 32 + lq;
        const bf16x8 kf = *(const bf16x8*)(
            lk[cur] + row * 128 + ((kd * 32 + hi * 16) ^ ((row & 7) << 4)));
        const bf16x8 qf = (kd == 0) ? qf0 : (kd == 1) ? qf1 : (kd == 2) ? qf2 : qf3;
        p = mfma32(kf, qf, p);
      }
      __builtin_amdgcn_s_setprio(0);
      // causal mask: kv = kvs + (r&3) + 8*(r>>2) + 4*hi ; mask if kv > qrow
      if (kvs + 31 > q0 + wv * 32) {
#pragma unroll
        for (int r = 0; r < 16; ++r) {
          const int kv = kvs + (r & 3) + 8 * (r >> 2) + 4 * hi;
          if (kv > qrow) p[r] = -1e30f;
        }
      }
      // p = exp2(s); the normalization constant cancels in O = acc / l
#pragma unroll
      for (int r = 0; r < 16; ++r) p[r] = __builtin_amdgcn_exp2f(p[r]);
      // lane-partial row-sum tree (cross-hi deferred to epilogue)
      float sr[8];
#pragma unroll
      for (int r = 0; r < 8; ++r) sr[r] = p[r] + p[r + 8];
#pragma unroll
      for (int r = 0; r < 4; ++r) sr[r] = sr[r] + sr[r + 4];
      l_r += (sr[0] + sr[1]) + (sr[2] + sr[3]);
      // pack P pairs: W[j][i] holds kv = 8j + 4hi + 2i + {0,1}
      unsigned W0a = pkbf(p[0], p[1]),   W0b = pkbf(p[2], p[3]);
      unsigned W1a = pkbf(p[4], p[5]),   W1b = pkbf(p[6], p[7]);
      unsigned W2a = pkbf(p[8], p[9]),   W2b = pkbf(p[10], p[11]);
      unsigned W3a = pkbf(p[12], p[13]), W3b = pkbf(p[14], p[15]);
      // PV: O^T += V^T . P  (2 k-steps of 16 kv)
#pragma unroll
      for (int ks = 0; ks < 2; ++ks) {
        unsigned a0u = ks ? W2a : W0a;
        unsigned a1u = ks ? W2b : W0b;
        unsigned b0u = ks ? W3a : W1a;
        unsigned b1u = ks ? W3b : W1b;
        plswap(a0u, b0u, hi);
        plswap(a1u, b1u, hi);
        const uint4 pw = {a0u, a1u, b0u, b1u};
        const bf16x8 pf = __builtin_bit_cast(bf16x8, pw);
        __builtin_amdgcn_s_setprio(1);
#pragma unroll
        for (int dt = 0; dt < 2; ++dt) {
          const int row = dt * 32 + lq;
          const bf16x8 vf = *(const bf16x8*)(
              lv[cur] + row * 128 +
              ((s * 64 + ks * 32 + hi * 16) ^ ((row & 7) << 4)));
          acco[dt] = mfma32(vf, pf, acco[dt]);
        }
        __builtin_amdgcn_s_setprio(0);
      }
    }
    if (ti + 1 < nt) WRITE_TILE(cur ^ 1);
    cur ^= 1;
  }
#undef LOAD_TILE
#undef WRITE_TILE
  // epilogue: lane = (q=qrow, d = (r&3)+8*(r>>2)+4*hi+32*dt)
  l_r += __shfl_xor(l_r, 32);  // combine hi-halves (disjoint kv slots)
  const int b = bh >> 4, h = bh & 15;
  const float inv = __builtin_amdgcn_rcpf(l_r);
  ushort* orow = out + ((size_t)(b * 2048 + qrow)) * 1024 + h * 64;
#pragma unroll
  for (int dt = 0; dt < 2; ++dt)
#pragma unroll
    for (int g2 = 0; g2 < 4; ++g2) {
      ushort4 st;
      st.x = __builtin_bit_cast(ushort, (__bf16)(acco[dt][4 * g2 + 0] * inv));
      st.y = __builtin_bit_cast(ushort, (__bf16)(acco[dt][4 * g2 + 1] * inv));
      st.z = __builtin_bit_cast(ushort, (__bf16)(acco[dt][4 * g2 + 2] * inv));
      st.w = __builtin_bit_cast(ushort, (__bf16)(acco[dt][4 * g2 + 3] * inv));
      *(ushort4*)(orow + dt * 32 + g2 * 8 + hi * 4) = st;
    }
}

extern "C" void kernel_launch(void* const* d_in, const int* in_sizes, int n_in,
                              void* d_out, int out_size, void* d_ws, size_t ws_size,
                              hipStream_t stream) {
  (void)in_sizes; (void)n_in; (void)out_size;
  const float* query = (const float*)d_in[0];
  const float* key = (const float*)d_in[1];
  const float* value = (const float*)d_in[2];
  const float* Wq = (const float*)d_in[4];
  const float* bq = (const float*)d_in[5];
  const float* Wk = (const float*)d_in[6];
  const float* bk = (const float*)d_in[7];
  const float* Wv = (const float*)d_in[8];
  const float* bv = (const float*)d_in[9];
  const float* Wo = (const float*)d_in[10];
  const float* bo = (const float*)d_in[11];

  char* ws = (char*)d_ws;
  const size_t SZA = (size_t)8192 * 1024 * 2;
  const size_t SZW = (size_t)1024 * 1024 * 2;
  ushort* qh = (ushort*)(ws + 0 * SZA);
  ushort* kh = (ushort*)(ws + 1 * SZA);
  ushort* vt = (ushort*)(ws + 2 * SZA);
  ushort* ao = (ushort*)(ws + 3 * SZA);
  dim3 bb(256), gg(512), ga(64, 16), ba(256);
  const float QS = 0.125f * 1.44269504088896f;  // 1/sqrt(64) * log2(e)

  if (ws_size >= 4 * SZA + 4 * SZW) {
    ushort* wq = (ushort*)(ws + 4 * SZA);
    ushort* wk = (ushort*)(ws + 4 * SZA + 1 * SZW);
    ushort* wv = (ushort*)(ws + 4 * SZA + 2 * SZW);
    ushort* wo = (ushort*)(ws + 4 * SZA + 3 * SZW);
    const int n8w = 1024 * 1024 / 8;
    hipLaunchKernelGGL(cvt4_k, dim3(n8w / 256, 4), bb, 0, stream, Wq, Wk, Wv, Wo, wq, n8w);
    hipLaunchKernelGGL((gemm_k<0, 0>), gg, bb, 0, stream, (const void*)query, wq, bq, (void*)qh, QS);
    hipLaunchKernelGGL((gemm_k<0, 0>), gg, bb, 0, stream, (const void*)key, wk, bk, (void*)kh, 1.0f);
    hipLaunchKernelGGL((gemm_k<0, 3>), gg, bb, 0, stream, (const void*)value, wv, bv, (void*)vt, 1.0f);
    hipLaunchKernelGGL(attn_k, ga, ba, 0, stream, qh, kh, vt, ao);
    hipLaunchKernelGGL((gemm_k<1, 2>), gg, bb, 0, stream, (const void*)ao, wo, bo, d_out, 1.0f);
  } else {
    hipLaunchKernelGGL((gemmF_k<0, 0>), dim3(64, 8), bb, 0, stream, (const void*)query, Wq, bq, (void*)qh, QS);
    hipLaunchKernelGGL((gemmF_k<0, 0>), dim3(64, 8), bb, 0, stream, (const void*)key, Wk, bk, (void*)kh, 1.0f);
    hipLaunchKernelGGL((gemmF_k<1, 0>), dim3(64, 8), bb, 0, stream, (const void*)value, Wv, bv, (void*)vt, 1.0f);
    hipLaunchKernelGGL(attn_k, ga, ba, 0, stream, qh, kh, vt, ao);
    hipLaunchKernelGGL((gemmF_k<2, 1>), dim3(64, 8), bb, 0, stream, (const void*)ao, Wo, bo, d_out, 1.0f);
  }
}